// Round 1
// baseline (305.028 us; speedup 1.0000x reference)
//
#include <hip/hip_runtime.h>

// ---------- problem dims ----------
constexpr int B_ = 16, C_ = 64, F_ = 40, T_ = 512;
constexpr int D_ = F_ * C_;              // 2560
constexpr float SCALE = 0.019764235376052372f;  // 1/sqrt(2560)

// ---------- types ----------
typedef __attribute__((ext_vector_type(8))) short s16x8;
typedef __attribute__((ext_vector_type(4))) short s16x4;
typedef __attribute__((ext_vector_type(2))) short s16x2;
typedef __attribute__((ext_vector_type(4))) float f32x4;

static __device__ __forceinline__ short f2bf(float f) {
  union { float f; unsigned u; } v; v.f = f;
  unsigned r = v.u + 0x7fffu + ((v.u >> 16) & 1u);   // RNE, no NaN inputs
  return (short)(r >> 16);
}

static __device__ __forceinline__ f32x4 mfma16(s16x8 a, s16x8 b, f32x4 c) {
  return __builtin_amdgcn_mfma_f32_16x16x32_bf16(a, b, c, 0, 0, 0);
}

// =====================================================================
// Kernel 1: 1x1-conv projections.  Per block: one (b, f, 256-wide t tile).
// Y[o][t] = sum_c W[o][c] * x[b][c][f][t]   for W in {Wq, Wk, Wv}
// Q,K stored [b][t][d] bf16 (d = f*64+o);  V stored [b][d][t] bf16.
// =====================================================================
__global__ __launch_bounds__(256) void proj_kernel(
    const float* __restrict__ x,
    const float* __restrict__ Wq, const float* __restrict__ Wk,
    const float* __restrict__ Wv,
    short* __restrict__ Q, short* __restrict__ K, short* __restrict__ V)
{
  constexpr int WS = 72;    // W lds row stride (shorts): 144B rows, 16B aligned
  constexpr int XS = 260;   // X lds row stride (shorts): quad-offset -> 2-way only
  __shared__ short Wl[3][64 * WS];
  __shared__ short Xl[64 * XS];

  const int b = blockIdx.z, f = blockIdx.y, tt = blockIdx.x;  // tt: 0..1
  const int tid = threadIdx.x;

  // stage W (bf16, row-major [o][c])
  for (int i = tid; i < 64 * 64; i += 256) {
    const int o = i >> 6, c = i & 63;
    Wl[0][o * WS + c] = f2bf(Wq[i]);
    Wl[1][o * WS + c] = f2bf(Wk[i]);
    Wl[2][o * WS + c] = f2bf(Wv[i]);
  }
  // stage X tile [64 c][256 t] as bf16 (coalesced float4 loads)
  const float* xp = x + (((size_t)b * 64) * 40 + f) * 512 + tt * 256;
  for (int i = tid; i < 64 * 64; i += 256) {      // i = float4 granule
    const int c = i >> 6, j = i & 63;
    const float4 v4 = *(const float4*)(xp + (size_t)c * (F_ * T_) + j * 4);
    s16x4 s4; s4[0] = f2bf(v4.x); s4[1] = f2bf(v4.y);
    s4[2] = f2bf(v4.z); s4[3] = f2bf(v4.w);
    *(s16x4*)&Xl[c * XS + j * 4] = s4;
  }
  __syncthreads();

  const int w = tid >> 6, lane = tid & 63;
  const int quad = lane >> 4, c16 = lane & 15;
  const int tl = w * 64;                           // wave's t-base in tile

  // B-fragments (X), shared by all three projections.
  // b_frag[j] = X[c = ks*32+quad*8+j][t]  (gathered: c is the LDS row)
  s16x8 bfrag[4][2];
  #pragma unroll
  for (int ni = 0; ni < 4; ++ni)
    #pragma unroll
    for (int ks = 0; ks < 2; ++ks) {
      const int t = tl + ni * 16 + c16;
      const int cb = ks * 32 + quad * 8;
      s16x8 tmp;
      #pragma unroll
      for (int j = 0; j < 8; ++j) tmp[j] = Xl[(cb + j) * XS + t];
      bfrag[ni][ks] = tmp;
    }

  for (int p = 0; p < 3; ++p) {
    f32x4 acc[4][4] = {};
    #pragma unroll
    for (int ks = 0; ks < 2; ++ks) {
      s16x8 afrag[4];
      #pragma unroll
      for (int mi = 0; mi < 4; ++mi)
        afrag[mi] = *(const s16x8*)&Wl[p][(mi * 16 + c16) * WS + ks * 32 + quad * 8];
      #pragma unroll
      for (int mi = 0; mi < 4; ++mi)
        #pragma unroll
        for (int ni = 0; ni < 4; ++ni)
          acc[mi][ni] = mfma16(afrag[mi], bfrag[ni][ks], acc[mi][ni]);
    }
    // D[m=o][n=t]: col(n)=c16 -> t, rows = quad*4+reg -> 4 consecutive o
    if (p < 2) {
      short* outp = (p == 0) ? Q : K;
      #pragma unroll
      for (int mi = 0; mi < 4; ++mi)
        #pragma unroll
        for (int ni = 0; ni < 4; ++ni) {
          const int t = tt * 256 + tl + ni * 16 + c16;
          const int o = mi * 16 + quad * 4;
          s16x4 s4;
          #pragma unroll
          for (int r = 0; r < 4; ++r) s4[r] = f2bf(acc[mi][ni][r]);
          *(s16x4*)&outp[((size_t)(b * 512 + t)) * D_ + f * 64 + o] = s4;
        }
    } else {
      #pragma unroll
      for (int mi = 0; mi < 4; ++mi)
        #pragma unroll
        for (int ni = 0; ni < 4; ++ni) {
          const int t = tt * 256 + tl + ni * 16 + c16;
          #pragma unroll
          for (int r = 0; r < 4; ++r) {
            const int o = mi * 16 + quad * 4 + r;
            V[((size_t)(b * D_ + f * 64 + o)) * 512 + t] = f2bf(acc[mi][ni][r]);
          }
        }
    }
  }
}

// =====================================================================
// Kernel 2: S = Q K^T / sqrt(d).  128x128 tile, BK=32, NT layout.
// =====================================================================
__global__ __launch_bounds__(256) void scores_kernel(
    const short* __restrict__ Q, const short* __restrict__ K,
    float* __restrict__ S)
{
  __shared__ short As[128 * 32];
  __shared__ short Bs[128 * 32];
  const int b = blockIdx.y;
  const int mt = blockIdx.x >> 2, nt = blockIdx.x & 3;
  const int m0 = mt * 128, n0 = nt * 128;
  const int tid = threadIdx.x;
  const int w = tid >> 6, lane = tid & 63, quad = lane >> 4, c16 = lane & 15;
  const int wm = (w >> 1) * 64, wn = (w & 1) * 64;
  const int r0 = tid >> 2, cc8 = (tid & 3) * 8;

  const short* qb = Q + (size_t)b * 512 * D_;
  const short* kb = K + (size_t)b * 512 * D_;
  const short* qrow0 = qb + (size_t)(m0 + r0) * D_ + cc8;
  const short* qrow1 = qb + (size_t)(m0 + 64 + r0) * D_ + cc8;
  const short* krow0 = kb + (size_t)(n0 + r0) * D_ + cc8;
  const short* krow1 = kb + (size_t)(n0 + 64 + r0) * D_ + cc8;

  f32x4 acc[4][4] = {};
  s16x8 a0 = *(const s16x8*)(qrow0);
  s16x8 a1 = *(const s16x8*)(qrow1);
  s16x8 b0 = *(const s16x8*)(krow0);
  s16x8 b1 = *(const s16x8*)(krow1);

  constexpr int NK = D_ / 32;   // 80
  for (int kk = 0; kk < NK; ++kk) {
    __syncthreads();
    *(s16x8*)&As[r0 * 32 + cc8] = a0;
    *(s16x8*)&As[(64 + r0) * 32 + cc8] = a1;
    *(s16x8*)&Bs[r0 * 32 + cc8] = b0;
    *(s16x8*)&Bs[(64 + r0) * 32 + cc8] = b1;
    __syncthreads();
    if (kk + 1 < NK) {                 // prefetch next tile (overlaps MFMA)
      const int off = (kk + 1) * 32;
      a0 = *(const s16x8*)(qrow0 + off);
      a1 = *(const s16x8*)(qrow1 + off);
      b0 = *(const s16x8*)(krow0 + off);
      b1 = *(const s16x8*)(krow1 + off);
    }
    s16x8 am[4], bm[4];
    #pragma unroll
    for (int mi = 0; mi < 4; ++mi)
      am[mi] = *(const s16x8*)&As[(wm + mi * 16 + c16) * 32 + quad * 8];
    #pragma unroll
    for (int ni = 0; ni < 4; ++ni)
      bm[ni] = *(const s16x8*)&Bs[(wn + ni * 16 + c16) * 32 + quad * 8];
    #pragma unroll
    for (int mi = 0; mi < 4; ++mi)
      #pragma unroll
      for (int ni = 0; ni < 4; ++ni)
        acc[mi][ni] = mfma16(am[mi], bm[ni], acc[mi][ni]);
  }

  float* sp = S + (size_t)b * 512 * 512;
  #pragma unroll
  for (int mi = 0; mi < 4; ++mi)
    #pragma unroll
    for (int ni = 0; ni < 4; ++ni) {
      const int kcol = n0 + wn + ni * 16 + c16;
      const int qrow = m0 + wm + mi * 16 + quad * 4;
      #pragma unroll
      for (int r = 0; r < 4; ++r)
        sp[(size_t)(qrow + r) * 512 + kcol] = acc[mi][ni][r] * SCALE;
    }
}

// =====================================================================
// Kernel 3: row softmax, S fp32 -> A bf16.  One block per (b, q) row.
// =====================================================================
__global__ __launch_bounds__(256) void softmax_kernel(
    const float* __restrict__ S, short* __restrict__ A)
{
  const int b = blockIdx.y, q = blockIdx.x;
  const int tid = threadIdx.x, w = tid >> 6, lane = tid & 63;
  const float* row = S + ((size_t)b * 512 + q) * 512;
  float2 v = *(const float2*)(row + tid * 2);

  float m = fmaxf(v.x, v.y);
  #pragma unroll
  for (int off = 1; off < 64; off <<= 1) m = fmaxf(m, __shfl_xor(m, off));
  __shared__ float redm[4], reds[4];
  if (lane == 0) redm[w] = m;
  __syncthreads();
  m = fmaxf(fmaxf(redm[0], redm[1]), fmaxf(redm[2], redm[3]));

  const float e0 = __expf(v.x - m), e1 = __expf(v.y - m);
  float s = e0 + e1;
  #pragma unroll
  for (int off = 1; off < 64; off <<= 1) s += __shfl_xor(s, off);
  if (lane == 0) reds[w] = s;
  __syncthreads();
  s = (reds[0] + reds[1]) + (reds[2] + reds[3]);

  const float inv = 1.0f / s;
  s16x2 o2; o2[0] = f2bf(e0 * inv); o2[1] = f2bf(e1 * inv);
  *(s16x2*)&A[((size_t)b * 512 + q) * 512 + tid * 2] = o2;
}

// =====================================================================
// Kernel 4: out = A @ V.  A [b][q][k] bf16, V as Vt [b][d][t] bf16.
// Epilogue writes fp32 directly in [b][c][f][t] via float4 (regs = 4
// consecutive t).
// =====================================================================
__global__ __launch_bounds__(256) void pv_kernel(
    const short* __restrict__ A, const short* __restrict__ V,
    float* __restrict__ out)
{
  __shared__ short As[128 * 32];
  __shared__ short Bs[128 * 32];
  const int b = blockIdx.y;
  const int mt = blockIdx.x / 20, dt = blockIdx.x % 20;
  const int m0 = mt * 128, n0 = dt * 128;
  const int tid = threadIdx.x;
  const int w = tid >> 6, lane = tid & 63, quad = lane >> 4, c16 = lane & 15;
  const int wm = (w >> 1) * 64, wn = (w & 1) * 64;
  const int r0 = tid >> 2, cc8 = (tid & 3) * 8;

  const short* ab = A + (size_t)b * 512 * 512;
  const short* vb = V + (size_t)b * D_ * 512;
  const short* arow0 = ab + (size_t)(m0 + r0) * 512 + cc8;
  const short* arow1 = ab + (size_t)(m0 + 64 + r0) * 512 + cc8;
  const short* vrow0 = vb + (size_t)(n0 + r0) * 512 + cc8;
  const short* vrow1 = vb + (size_t)(n0 + 64 + r0) * 512 + cc8;

  f32x4 acc[4][4] = {};
  s16x8 a0 = *(const s16x8*)(arow0);
  s16x8 a1 = *(const s16x8*)(arow1);
  s16x8 b0 = *(const s16x8*)(vrow0);
  s16x8 b1 = *(const s16x8*)(vrow1);

  constexpr int NK = 512 / 32;   // 16
  for (int kk = 0; kk < NK; ++kk) {
    __syncthreads();
    *(s16x8*)&As[r0 * 32 + cc8] = a0;
    *(s16x8*)&As[(64 + r0) * 32 + cc8] = a1;
    *(s16x8*)&Bs[r0 * 32 + cc8] = b0;
    *(s16x8*)&Bs[(64 + r0) * 32 + cc8] = b1;
    __syncthreads();
    if (kk + 1 < NK) {
      const int off = (kk + 1) * 32;
      a0 = *(const s16x8*)(arow0 + off);
      a1 = *(const s16x8*)(arow1 + off);
      b0 = *(const s16x8*)(vrow0 + off);
      b1 = *(const s16x8*)(vrow1 + off);
    }
    s16x8 am[4], bm[4];
    #pragma unroll
    for (int mi = 0; mi < 4; ++mi)
      am[mi] = *(const s16x8*)&As[(wm + mi * 16 + c16) * 32 + quad * 8];
    #pragma unroll
    for (int ni = 0; ni < 4; ++ni)
      bm[ni] = *(const s16x8*)&Bs[(wn + ni * 16 + c16) * 32 + quad * 8];
    #pragma unroll
    for (int mi = 0; mi < 4; ++mi)
      #pragma unroll
      for (int ni = 0; ni < 4; ++ni)
        acc[mi][ni] = mfma16(am[mi], bm[ni], acc[mi][ni]);
  }

  #pragma unroll
  for (int mi = 0; mi < 4; ++mi)
    #pragma unroll
    for (int ni = 0; ni < 4; ++ni) {
      const int d = n0 + wn + ni * 16 + c16;
      const int ff = d >> 6, cc = d & 63;
      const int t = m0 + wm + mi * 16 + quad * 4;
      float4 o4;
      o4.x = acc[mi][ni][0]; o4.y = acc[mi][ni][1];
      o4.z = acc[mi][ni][2]; o4.w = acc[mi][ni][3];
      *(float4*)&out[(((size_t)b * 64 + cc) * 40 + ff) * 512 + t] = o4;
    }
}

// =====================================================================
extern "C" void kernel_launch(void* const* d_in, const int* in_sizes, int n_in,
                              void* d_out, int out_size, void* d_ws, size_t ws_size,
                              hipStream_t stream)
{
  const float* x  = (const float*)d_in[0];
  const float* Wq = (const float*)d_in[1];
  const float* Wk = (const float*)d_in[2];
  const float* Wv = (const float*)d_in[3];
  float* out = (float*)d_out;

  // workspace layout (bytes):
  //   Q  [16][512][2560] bf16 : 41,943,040
  //   K  [16][512][2560] bf16 : 41,943,040
  //   Vt [16][2560][512] bf16 : 41,943,040
  //   S  [16][512][512]  fp32 : 16,777,216
  //   A  [16][512][512]  bf16 :  8,388,608   (total 150,994,944)
  char* ws = (char*)d_ws;
  constexpr size_t QB = (size_t)B_ * T_ * D_ * 2;
  short* Q  = (short*)(ws);
  short* Kt = (short*)(ws + QB);
  short* Vt = (short*)(ws + 2 * QB);
  float* S  = (float*)(ws + 3 * QB);
  short* At = (short*)(ws + 3 * QB + (size_t)B_ * T_ * T_ * 4);

  proj_kernel<<<dim3(2, 40, 16), 256, 0, stream>>>(x, Wq, Wk, Wv, Q, Kt, Vt);
  scores_kernel<<<dim3(16, 16), 256, 0, stream>>>(Q, Kt, S);
  softmax_kernel<<<dim3(512, 16), 256, 0, stream>>>(S, At);
  pv_kernel<<<dim3(80, 16), 256, 0, stream>>>(At, Vt, out);
}